// Round 1
// baseline (118.351 us; speedup 1.0000x reference)
//
#include <hip/hip_runtime.h>

typedef float fx4 __attribute__((ext_vector_type(4)));
typedef short s16x8 __attribute__((ext_vector_type(8)));
typedef __bf16 bfx8 __attribute__((ext_vector_type(8)));

#define KN 1024
#define TT 16384
#define NOUT 16382

// ws layout (bytes)
#define XTP_BYTES (128u * 32u * 9216u)      // 37,748,736
#define W0_OFF XTP_BYTES
#define W1_OFF (W0_OFF + 2097152u)
#define B1_OFF (W1_OFF + 2097152u)          // total 42,074,112

__device__ __forceinline__ unsigned short f2bf(float f) {
  return __builtin_bit_cast(unsigned short, (__bf16)f);
}

__device__ __forceinline__ void gll16(const void* g, void* l) {
  __builtin_amdgcn_global_load_lds(
      (const __attribute__((address_space(1))) void*)g,
      (__attribute__((address_space(3))) void*)l, 16, 0, 0);
}

// ---- kernel 1: adjacency bitmask rows (1024 bits = 32 u32 per node) ----
__global__ __launch_bounds__(256) void k_masks(const float* __restrict__ A,
                                               unsigned* __restrict__ B1) {
  int k = blockIdx.x;
  int tid = threadIdx.x;
  int wv = tid >> 6, lane = tid & 63;
  for (int i = 0; i < 4; ++i) {
    int n = i * 256 + wv * 64 + lane;
    bool bit = (A[(size_t)k * KN + n] > 0.5f) && (n != k);
    unsigned long long m = __ballot(bit);
    if (lane == 0) {
      B1[k * 32 + i * 8 + wv * 2]     = (unsigned)m;
      B1[k * 32 + i * 8 + wv * 2 + 1] = (unsigned)(m >> 32);
    }
  }
}

// ---- kernel 2: build W0', W1' (bf16) pre-packed in MFMA A-tile layout ----
// W0' = beta0[0]/deg1 * dist1 + beta1[0]/deg2 * dist2 + alpha[0] * I
// W1' = beta0[1]/deg1 * dist1 + beta1[1]/deg2 * dist2 + alpha[1] * I
// packed idx (u16): (((mb*32+ks)*4+kb)*128 + mloc)*8 + ii,  n = ks*32+kb*8+ii, mb=k>>7
__global__ __launch_bounds__(256) void k_weights(const unsigned* __restrict__ B1,
                                                 const float* __restrict__ alpha,
                                                 const float* __restrict__ beta0,
                                                 const float* __restrict__ beta1,
                                                 unsigned short* __restrict__ W0p,
                                                 unsigned short* __restrict__ W1p) {
  __shared__ unsigned reach[32];
  __shared__ unsigned ex2[32];
  __shared__ unsigned short list[1056];
  __shared__ int nl;
  int k = blockIdx.x, tid = threadIdx.x;
  if (tid == 0) nl = 0;
  if (tid < 32) {
    unsigned r = B1[k * 32 + tid];
    if (tid == (k >> 5)) r |= 1u << (k & 31);  // reach = {k} | N(k)
    reach[tid] = r;
    ex2[tid] = 0;
  }
  __syncthreads();
  for (int m = tid; m < KN; m += 256)
    if ((reach[m >> 5] >> (m & 31)) & 1) {
      int i = atomicAdd(&nl, 1);
      list[i] = (unsigned short)m;
    }
  __syncthreads();
  int n2 = nl;
  for (int i = 0; i < n2; ++i) {
    int m = list[i];
    if (tid < 32) ex2[tid] |= B1[m * 32 + tid];   // union of N(m), m in reach
  }
  __syncthreads();
  if (tid < 32) ex2[tid] &= ~reach[tid];          // distance exactly 2
  __syncthreads();
  int d1 = 0, d2 = 0;
  for (int w = 0; w < 32; ++w) { d1 += __popc(reach[w]); d2 += __popc(ex2[w]); }
  d1 -= 1;  // remove self bit
  float rd1 = 1.0f / fmaxf((float)d1, 1.0f);
  float rd2 = 1.0f / fmaxf((float)d2, 1.0f);
  float c00 = beta0[0] * rd1, c01 = beta0[1] * rd1;
  float c10 = beta1[0] * rd2, c11 = beta1[1] * rd2;
  float a0 = alpha[0], a1 = alpha[1];
  int mb = k >> 7, mloc = k & 127;
  for (int q = 0; q < 4; ++q) {
    int n = tid * 4 + q;
    bool in1 = (((reach[n >> 5] >> (n & 31)) & 1) != 0) && (n != k);
    bool in2 = ((ex2[n >> 5] >> (n & 31)) & 1) != 0;
    float v0 = (in1 ? c00 : 0.f) + (in2 ? c10 : 0.f) + (n == k ? a0 : 0.f);
    float v1 = (in1 ? c01 : 0.f) + (in2 ? c11 : 0.f) + (n == k ? a1 : 0.f);
    int ks = n >> 5, kb = (n >> 3) & 3, ii = n & 7;
    size_t idx = ((((size_t)mb * 32 + ks) * 4 + kb) * 128 + mloc) * 8 + ii;
    W0p[idx] = f2bf(v0);
    W1p[idx] = f2bf(v1);
  }
}

// ---- kernel 3: X (f32 K x T) -> bf16 X^T packed B-tiles ----
// chunk(jb,ks) = [kb(4)][j(144)][i(8)] u16 = 9216 B; value = X[ks*32+kb*8+i][jb*128+j] (0 past T)
__global__ __launch_bounds__(256) void k_pack_x(const float* __restrict__ X,
                                                unsigned short* __restrict__ XTp) {
  __shared__ float Xs[32][145];
  int jb = blockIdx.x;  // 0..127
  int ks = blockIdx.y;  // 0..31
  int tid = threadIdx.x;
  for (int idx = tid; idx < 32 * 144; idx += 256) {
    int no = idx / 144, to = idx - no * 144;
    int t = jb * 128 + to;
    Xs[no][to] = (t < TT) ? X[(size_t)(ks * 32 + no) * TT + t] : 0.0f;
  }
  __syncthreads();
  unsigned short* dst = XTp + ((size_t)jb * 32 + ks) * 4608;
  for (int c = tid; c < 576; c += 256) {
    int kb = c / 144, j = c - kb * 144;
    unsigned v[4];
#pragma unroll
    for (int p = 0; p < 4; ++p) {
      unsigned short lo = f2bf(Xs[kb * 8 + p * 2][j]);
      unsigned short hi = f2bf(Xs[kb * 8 + p * 2 + 1][j]);
      v[p] = (unsigned)lo | ((unsigned)hi << 16);
    }
    uint4 w; w.x = v[0]; w.y = v[1]; w.z = v[2]; w.w = v[3];
    *reinterpret_cast<uint4*>(dst + (size_t)c * 8) = w;
  }
}

// ---- kernel 4: fused dual-A GEMM: Y[k,j] = (W0@X)[k,j+1] + (W1@X)[k,j] ----
// 128x128 tile, BK=32, 4 waves (2x2), 16x16x32 bf16 MFMA, double-buffered LDS
__global__ __launch_bounds__(256) void k_gemm(const unsigned short* __restrict__ W0p,
                                              const unsigned short* __restrict__ W1p,
                                              const unsigned short* __restrict__ XTp,
                                              float* __restrict__ Y) {
  __shared__ uint4 lds4[3200];  // 2 x 25600 B (A0 8K | A1 8K | B 9216)
  char* lds = (char*)lds4;
  int jb = blockIdx.x;  // 0..127 (j tile)
  int mb = blockIdx.y;  // 0..7   (k-node tile)
  int tid = threadIdx.x;
  int lane = tid & 63, wv = tid >> 6;
  int wm = wv >> 1, wn = wv & 1;
  const char* w0s = (const char*)W0p + (size_t)mb * 32 * 8192;
  const char* w1s = (const char*)W1p + (size_t)mb * 32 * 8192;
  const char* bsrc = (const char*)XTp + (size_t)jb * 32 * 9216;

  fx4 acc[4][4];
#pragma unroll
  for (int a = 0; a < 4; ++a)
#pragma unroll
    for (int b = 0; b < 4; ++b) acc[a][b] = (fx4){0.f, 0.f, 0.f, 0.f};

  auto stage = [&](int ks, int buf) {
    char* base = lds + buf * 25600;
    const char* s0 = w0s + (size_t)ks * 8192;
    const char* s1 = w1s + (size_t)ks * 8192;
    const char* sb = bsrc + (size_t)ks * 9216;
    for (int u = tid; u < 1600; u += 256) {
      if (u < 512)       gll16(s0 + (size_t)u * 16, base + u * 16);
      else if (u < 1024) gll16(s1 + (size_t)(u - 512) * 16, base + u * 16);
      else               gll16(sb + (size_t)(u - 1024) * 16, base + u * 16);
    }
  };

  stage(0, 0);
  __syncthreads();

  int kb = lane >> 4, ml = lane & 15;
  for (int ks = 0; ks < 32; ++ks) {
    int buf = ks & 1;
    if (ks + 1 < 32) stage(ks + 1, buf ^ 1);
    const char* Abase0 = lds + buf * 25600;
    const char* Abase1 = Abase0 + 8192;
    const char* Bbase  = Abase0 + 16384;
    s16x8 a0[4], a1[4], bu[4], bsh[4];
#pragma unroll
    for (int mf = 0; mf < 4; ++mf) {
      int m = wm * 64 + mf * 16 + ml;
      a0[mf] = *(const s16x8*)(Abase0 + (kb * 128 + m) * 16);
      a1[mf] = *(const s16x8*)(Abase1 + (kb * 128 + m) * 16);
    }
#pragma unroll
    for (int nf = 0; nf < 4; ++nf) {
      int j = wn * 64 + nf * 16 + ml;
      bu[nf]  = *(const s16x8*)(Bbase + (kb * 144 + j) * 16);       // col j   -> W1
      bsh[nf] = *(const s16x8*)(Bbase + (kb * 144 + j + 1) * 16);   // col j+1 -> W0
    }
#pragma unroll
    for (int mf = 0; mf < 4; ++mf)
#pragma unroll
      for (int nf = 0; nf < 4; ++nf) {
        acc[mf][nf] = __builtin_amdgcn_mfma_f32_16x16x32_bf16(
            __builtin_bit_cast(bfx8, a1[mf]), __builtin_bit_cast(bfx8, bu[nf]),
            acc[mf][nf], 0, 0, 0);
        acc[mf][nf] = __builtin_amdgcn_mfma_f32_16x16x32_bf16(
            __builtin_bit_cast(bfx8, a0[mf]), __builtin_bit_cast(bfx8, bsh[nf]),
            acc[mf][nf], 0, 0, 0);
      }
    __syncthreads();
  }

  // epilogue: C/D layout col=lane&15, row=(lane>>4)*4+r
  int j0 = jb * 128 + wn * 64;
  int m0 = mb * 128 + wm * 64;
#pragma unroll
  for (int mf = 0; mf < 4; ++mf)
#pragma unroll
    for (int nf = 0; nf < 4; ++nf) {
      int j = j0 + nf * 16 + ml;
      if (j < NOUT) {
        int mrow = m0 + mf * 16 + (lane >> 4) * 4;
#pragma unroll
        for (int r = 0; r < 4; ++r)
          Y[(size_t)(mrow + r) * NOUT + j] = acc[mf][nf][r];
      }
    }
}

extern "C" void kernel_launch(void* const* d_in, const int* in_sizes, int n_in,
                              void* d_out, int out_size, void* d_ws, size_t ws_size,
                              hipStream_t stream) {
  const float* X     = (const float*)d_in[0];
  const float* A     = (const float*)d_in[1];
  const float* alpha = (const float*)d_in[2];
  const float* beta0 = (const float*)d_in[3];
  const float* beta1 = (const float*)d_in[4];
  float* Y = (float*)d_out;
  char* ws = (char*)d_ws;
  unsigned short* XTp = (unsigned short*)ws;
  unsigned short* W0p = (unsigned short*)(ws + W0_OFF);
  unsigned short* W1p = (unsigned short*)(ws + W1_OFF);
  unsigned* B1        = (unsigned*)(ws + B1_OFF);

  k_masks<<<dim3(1024), dim3(256), 0, stream>>>(A, B1);
  k_weights<<<dim3(1024), dim3(256), 0, stream>>>(B1, alpha, beta0, beta1, W0p, W1p);
  k_pack_x<<<dim3(128, 32), dim3(256), 0, stream>>>(X, XTp);
  k_gemm<<<dim3(128, 8), dim3(256), 0, stream>>>(W0p, W1p, XTp, Y);
}

// Round 2
// 102.705 us; speedup vs baseline: 1.1523x; 1.1523x over previous
//
#include <hip/hip_runtime.h>

typedef float fx4 __attribute__((ext_vector_type(4)));
typedef short s16x8 __attribute__((ext_vector_type(8)));
typedef __bf16 bfx8 __attribute__((ext_vector_type(8)));

#define KN 1024
#define TT 16384
#define NOUT 16382
#define NKT 32   // K' = 2048, tiles of 64

// ws layout: Bpk (64 MiB) at 0; Apk (4 MiB) at 64 MiB; B1 bitmasks alias Bpk start
#define APK_OFF 67108864u

__device__ __forceinline__ unsigned short f2bf(float f) {
  return __builtin_bit_cast(unsigned short, (__bf16)f);
}

__device__ __forceinline__ void gll16(const void* g, void* l) {
  __builtin_amdgcn_global_load_lds(
      (const __attribute__((address_space(1))) void*)g,
      (__attribute__((address_space(3))) void*)l, 16, 0, 0);
}

// ---- kernel 1: adjacency bitmask rows (1024 bits = 32 u32 per node) ----
__global__ __launch_bounds__(256) void k_masks(const float* __restrict__ A,
                                               unsigned* __restrict__ B1) {
  int k = blockIdx.x;
  int tid = threadIdx.x;
  int wv = tid >> 6, lane = tid & 63;
  for (int i = 0; i < 4; ++i) {
    int n = i * 256 + wv * 64 + lane;
    bool bit = (A[(size_t)k * KN + n] > 0.5f) && (n != k);
    unsigned long long m = __ballot(bit);
    if (lane == 0) {
      B1[k * 32 + i * 8 + wv * 2]     = (unsigned)m;
      B1[k * 32 + i * 8 + wv * 2 + 1] = (unsigned)(m >> 32);
    }
  }
}

// ---- kernel 2: build interleaved Wc (bf16) pre-packed in MFMA A-tile layout ----
// k' = 2n + s: s=0 -> coeffs idx0 (pairs with X[.,j+1]), s=1 -> coeffs idx1 (X[.,j])
// idx = ((((mb*32+kt)*2+qk)*4+kb)*256 + rloc)*8 + ii, k' = kt*64+qk*32+kb*8+ii, mb=k>>8
__global__ __launch_bounds__(256) void k_weights(const unsigned* __restrict__ B1,
                                                 const float* __restrict__ alpha,
                                                 const float* __restrict__ beta0,
                                                 const float* __restrict__ beta1,
                                                 unsigned short* __restrict__ Wc) {
  __shared__ unsigned reach[32];
  __shared__ unsigned ex2[32];
  __shared__ unsigned short list[1056];
  __shared__ int nl;
  int k = blockIdx.x, tid = threadIdx.x;
  if (tid == 0) nl = 0;
  if (tid < 32) {
    unsigned r = B1[k * 32 + tid];
    if (tid == (k >> 5)) r |= 1u << (k & 31);  // reach = {k} | N(k)
    reach[tid] = r;
    ex2[tid] = 0;
  }
  __syncthreads();
  for (int m = tid; m < KN; m += 256)
    if ((reach[m >> 5] >> (m & 31)) & 1) {
      int i = atomicAdd(&nl, 1);
      list[i] = (unsigned short)m;
    }
  __syncthreads();
  int n2 = nl;
  for (int i = 0; i < n2; ++i) {
    int m = list[i];
    if (tid < 32) ex2[tid] |= B1[m * 32 + tid];   // union of N(m), m in reach
  }
  __syncthreads();
  if (tid < 32) ex2[tid] &= ~reach[tid];          // distance exactly 2
  __syncthreads();
  int d1 = 0, d2 = 0;
  for (int w = 0; w < 32; ++w) { d1 += __popc(reach[w]); d2 += __popc(ex2[w]); }
  d1 -= 1;  // remove self bit
  float rd1 = 1.0f / fmaxf((float)d1, 1.0f);
  float rd2 = 1.0f / fmaxf((float)d2, 1.0f);
  float c00 = beta0[0] * rd1, c01 = beta0[1] * rd1;
  float c10 = beta1[0] * rd2, c11 = beta1[1] * rd2;
  float a0 = alpha[0], a1 = alpha[1];
  int mb = k >> 8, rloc = k & 255;
  for (int q = 0; q < 4; ++q) {
    int n = tid * 4 + q;
    bool in1 = (((reach[n >> 5] >> (n & 31)) & 1) != 0) && (n != k);
    bool in2 = ((ex2[n >> 5] >> (n & 31)) & 1) != 0;
    float v0 = (in1 ? c00 : 0.f) + (in2 ? c10 : 0.f) + (n == k ? a0 : 0.f);
    float v1 = (in1 ? c01 : 0.f) + (in2 ? c11 : 0.f) + (n == k ? a1 : 0.f);
    int kt = n >> 5, qk = (n >> 4) & 1, kb = (n >> 2) & 3, ii = (n & 3) * 2;
    size_t idx = ((((size_t)(mb * 32 + kt) * 2 + qk) * 4 + kb) * 256 + rloc) * 8 + ii;
    unsigned pair = (unsigned)f2bf(v0) | ((unsigned)f2bf(v1) << 16);
    *reinterpret_cast<unsigned*>(Wc + idx) = pair;
  }
}

// ---- kernel 3: X (f32 K x T) -> interleaved bf16 X2 packed B-tiles ----
// group G = ((((jb*32+kt)*2+qk)*4+kb)*256 + col); elem ii: k'=kt*64+qk*32+kb*8+ii,
// m=k'>>1, s=k'&1, value = X[m, jb*256+col + 1-s] (0 past T)
__global__ __launch_bounds__(256) void k_pack_x2(const float* __restrict__ X,
                                                 unsigned short* __restrict__ Bpk) {
  int G = blockIdx.x * 256 + threadIdx.x;   // 0 .. 4,194,303
  int col = G & 255;
  int kb  = (G >> 8) & 3;
  int qk  = (G >> 10) & 1;
  int kt  = (G >> 11) & 31;
  int jb  = G >> 16;
  int j   = jb * 256 + col;
  int mbase = kt * 32 + qk * 16 + kb * 4;
  unsigned v[4];
#pragma unroll
  for (int p = 0; p < 4; ++p) {
    int m = mbase + p;
    int j1 = j + 1;
    float f0 = (j1 < TT) ? X[(size_t)m * TT + j1] : 0.0f;  // s=0
    float f1 = X[(size_t)m * TT + j];                      // s=1
    v[p] = (unsigned)f2bf(f0) | ((unsigned)f2bf(f1) << 16);
  }
  uint4 w; w.x = v[0]; w.y = v[1]; w.z = v[2]; w.w = v[3];
  *reinterpret_cast<uint4*>(Bpk + (size_t)G * 8) = w;
}

// ---- kernel 4: 256x256 8-phase GEMM, K'=2048, counted vmcnt ----
__global__ __launch_bounds__(512, 2) void k_gemm(const char* __restrict__ Apk,
                                                 const char* __restrict__ Bpk,
                                                 float* __restrict__ Y) {
  __shared__ char lds[131072];  // 2 buf x { A 32K (h0|h1) | B 32K (h0|h1) }
  int bid = blockIdx.x;
  int swz = (bid & 7) * 32 + (bid >> 3);   // XCD-contiguous work chunks
  int jb = swz >> 2, mb = swz & 3;
  int tid = threadIdx.x;
  int lane = tid & 63, wv = tid >> 6;
  int wm = wv >> 2, wn = wv & 3;           // wave out: rows wm*128, cols wn*64
  int kb = lane >> 4, ml = lane & 15;
  const char* Asrc = Apk + (size_t)mb * (NKT * 2 * 16384);
  const char* Bsrc = Bpk + (size_t)jb * (NKT * 2 * 16384);

  fx4 acc[2][4][4];
#pragma unroll
  for (int q = 0; q < 2; ++q)
#pragma unroll
    for (int a = 0; a < 4; ++a)
#pragma unroll
      for (int b = 0; b < 4; ++b) acc[q][a][b] = (fx4){0.f, 0.f, 0.f, 0.f};

  auto stage_half = [&](int tile, int isB, int qh) {
    char* dst = lds + (tile & 1) * 65536 + isB * 32768 + qh * 16384;
    const char* src = (isB ? Bsrc : Asrc) + ((size_t)tile * 2 + qh) * 16384;
    gll16(src + tid * 16, dst + tid * 16);
    gll16(src + (size_t)(tid + 512) * 16, dst + (tid + 512) * 16);
  };

  // prologue: 6 halves (12 loads/thread); vmcnt(8) -> tile0 h0 (A+B) landed
  stage_half(0, 0, 0); stage_half(0, 1, 0);
  stage_half(0, 0, 1); stage_half(0, 1, 1);
  stage_half(1, 0, 0); stage_half(1, 1, 0);
  asm volatile("s_waitcnt vmcnt(8)" ::: "memory");
  __builtin_amdgcn_s_barrier();

  for (int kt = 0; kt < NKT; ++kt) {
    const char* base = lds + (kt & 1) * 65536;
#pragma unroll
    for (int qk = 0; qk < 2; ++qk) {
#pragma unroll
      for (int qm = 0; qm < 2; ++qm) {
        // --- ds-read subtile (8 x ds_read_b128) ---
        const char* Ah = base + qk * 16384;
        const char* Bh = base + 32768 + qk * 16384;
        s16x8 a[4], b[4];
#pragma unroll
        for (int mf = 0; mf < 4; ++mf)
          a[mf] = *(const s16x8*)(Ah + (size_t)(kb * 256 + wm * 128 + qm * 64 + mf * 16 + ml) * 16);
#pragma unroll
        for (int nf = 0; nf < 4; ++nf)
          b[nf] = *(const s16x8*)(Bh + (size_t)(kb * 256 + wn * 64 + nf * 16 + ml) * 16);
        // --- stage one half-tile (2 x global_load_lds, modular tail) ---
        {
          int sq = qk * 2 + qm;                   // 0:Ah1(kt+1) 1:Bh1(kt+1) 2:Ah0(kt+2) 3:Bh0(kt+2)
          int t2 = (kt + 1 + (sq >> 1)) & (NKT - 1);
          stage_half(t2, sq & 1, (sq < 2) ? 1 : 0);
        }
        if (qm == 1) asm volatile("s_waitcnt vmcnt(8)" ::: "memory");
        __builtin_amdgcn_s_barrier();
        asm volatile("s_waitcnt lgkmcnt(0)" ::: "memory");
        __builtin_amdgcn_s_setprio(1);
#pragma unroll
        for (int mf = 0; mf < 4; ++mf)
#pragma unroll
          for (int nf = 0; nf < 4; ++nf)
            acc[qm][mf][nf] = __builtin_amdgcn_mfma_f32_16x16x32_bf16(
                __builtin_bit_cast(bfx8, a[mf]), __builtin_bit_cast(bfx8, b[nf]),
                acc[qm][mf][nf], 0, 0, 0);
        __builtin_amdgcn_s_setprio(0);
        __builtin_amdgcn_s_barrier();
      }
    }
  }

  // epilogue: C/D layout col=lane&15, row=(lane>>4)*4+r
  int c0 = jb * 256 + wn * 64;
  int r0 = mb * 256 + wm * 128;
#pragma unroll
  for (int qm = 0; qm < 2; ++qm)
#pragma unroll
    for (int mf = 0; mf < 4; ++mf)
#pragma unroll
      for (int nf = 0; nf < 4; ++nf) {
        int c = c0 + nf * 16 + ml;
        if (c < NOUT) {
          int r = r0 + qm * 64 + mf * 16 + (lane >> 4) * 4;
#pragma unroll
          for (int i = 0; i < 4; ++i)
            Y[(size_t)(r + i) * NOUT + c] = acc[qm][mf][nf][i];
        }
      }
}

extern "C" void kernel_launch(void* const* d_in, const int* in_sizes, int n_in,
                              void* d_out, int out_size, void* d_ws, size_t ws_size,
                              hipStream_t stream) {
  const float* X     = (const float*)d_in[0];
  const float* A     = (const float*)d_in[1];
  const float* alpha = (const float*)d_in[2];
  const float* beta0 = (const float*)d_in[3];
  const float* beta1 = (const float*)d_in[4];
  float* Y = (float*)d_out;
  char* ws = (char*)d_ws;
  char* Bpk = ws;                       // 64 MiB
  char* Apk = ws + APK_OFF;             // 4 MiB
  unsigned* B1 = (unsigned*)ws;         // 128 KiB, aliases Bpk (dead before pack)

  k_masks<<<dim3(1024), dim3(256), 0, stream>>>(A, B1);
  k_weights<<<dim3(1024), dim3(256), 0, stream>>>(B1, alpha, beta0, beta1,
                                                  (unsigned short*)Apk);
  k_pack_x2<<<dim3(16384), dim3(256), 0, stream>>>(X, (unsigned short*)Bpk);
  k_gemm<<<dim3(256), dim3(512), 0, stream>>>(Apk, Bpk, Y);
}

// Round 3
// 93.827 us; speedup vs baseline: 1.2614x; 1.0946x over previous
//
#include <hip/hip_runtime.h>

typedef float fx4 __attribute__((ext_vector_type(4)));
typedef short s16x8 __attribute__((ext_vector_type(8)));
typedef __bf16 bfx8 __attribute__((ext_vector_type(8)));

#define KN 1024
#define TT 16384
#define NOUT 16382
#define NKT 32   // K' = 2048, tiles of 64

// ws layout: Bpk (64 MiB) at 0; Apk (4 MiB) at 64 MiB; B1 bitmasks alias Bpk start
#define APK_OFF 67108864u

__device__ __forceinline__ unsigned short f2bf(float f) {
  return __builtin_bit_cast(unsigned short, (__bf16)f);
}

__device__ __forceinline__ void gll16(const void* g, void* l) {
  __builtin_amdgcn_global_load_lds(
      (const __attribute__((address_space(1))) void*)g,
      (__attribute__((address_space(3))) void*)l, 16, 0, 0);
}

// ---- kernel 1: adjacency bitmask rows (1024 bits = 32 u32 per node) ----
__global__ __launch_bounds__(256) void k_masks(const float* __restrict__ A,
                                               unsigned* __restrict__ B1) {
  int k = blockIdx.x;
  int tid = threadIdx.x;
  int wv = tid >> 6, lane = tid & 63;
  for (int i = 0; i < 4; ++i) {
    int n = i * 256 + wv * 64 + lane;
    bool bit = (A[(size_t)k * KN + n] > 0.5f) && (n != k);
    unsigned long long m = __ballot(bit);
    if (lane == 0) {
      B1[k * 32 + i * 8 + wv * 2]     = (unsigned)m;
      B1[k * 32 + i * 8 + wv * 2 + 1] = (unsigned)(m >> 32);
    }
  }
}

// ---- kernel 2: build interleaved Wc (bf16) pre-packed in MFMA A-tile layout ----
// k' = 2n + s: s=0 -> coeffs idx0 (pairs with X[.,j+1]), s=1 -> coeffs idx1 (X[.,j])
__global__ __launch_bounds__(256) void k_weights(const unsigned* __restrict__ B1,
                                                 const float* __restrict__ alpha,
                                                 const float* __restrict__ beta0,
                                                 const float* __restrict__ beta1,
                                                 unsigned short* __restrict__ Wc) {
  __shared__ unsigned reach[32];
  __shared__ unsigned ex2[32];
  __shared__ unsigned short list[1056];
  __shared__ int nl;
  int k = blockIdx.x, tid = threadIdx.x;
  if (tid == 0) nl = 0;
  if (tid < 32) {
    unsigned r = B1[k * 32 + tid];
    if (tid == (k >> 5)) r |= 1u << (k & 31);  // reach = {k} | N(k)
    reach[tid] = r;
    ex2[tid] = 0;
  }
  __syncthreads();
  for (int m = tid; m < KN; m += 256)
    if ((reach[m >> 5] >> (m & 31)) & 1) {
      int i = atomicAdd(&nl, 1);
      list[i] = (unsigned short)m;
    }
  __syncthreads();
  int n2 = nl;
  for (int i = 0; i < n2; ++i) {
    int m = list[i];
    if (tid < 32) ex2[tid] |= B1[m * 32 + tid];   // union of N(m), m in reach
  }
  __syncthreads();
  if (tid < 32) ex2[tid] &= ~reach[tid];          // distance exactly 2
  __syncthreads();
  int d1 = 0, d2 = 0;
  for (int w = 0; w < 32; ++w) { d1 += __popc(reach[w]); d2 += __popc(ex2[w]); }
  d1 -= 1;  // remove self bit
  float rd1 = 1.0f / fmaxf((float)d1, 1.0f);
  float rd2 = 1.0f / fmaxf((float)d2, 1.0f);
  float c00 = beta0[0] * rd1, c01 = beta0[1] * rd1;
  float c10 = beta1[0] * rd2, c11 = beta1[1] * rd2;
  float a0 = alpha[0], a1 = alpha[1];
  int mb = k >> 8, rloc = k & 255;
  for (int q = 0; q < 4; ++q) {
    int n = tid * 4 + q;
    bool in1 = (((reach[n >> 5] >> (n & 31)) & 1) != 0) && (n != k);
    bool in2 = ((ex2[n >> 5] >> (n & 31)) & 1) != 0;
    float v0 = (in1 ? c00 : 0.f) + (in2 ? c10 : 0.f) + (n == k ? a0 : 0.f);
    float v1 = (in1 ? c01 : 0.f) + (in2 ? c11 : 0.f) + (n == k ? a1 : 0.f);
    int kt = n >> 5, qk = (n >> 4) & 1, kb = (n >> 2) & 3, ii = (n & 3) * 2;
    size_t idx = ((((size_t)(mb * 32 + kt) * 2 + qk) * 4 + kb) * 256 + rloc) * 8 + ii;
    unsigned pair = (unsigned)f2bf(v0) | ((unsigned)f2bf(v1) << 16);
    *reinterpret_cast<unsigned*>(Wc + idx) = pair;
  }
}

// ---- kernel 3: X (f32 K x T) -> interleaved bf16 X2 packed B-tiles ----
__global__ __launch_bounds__(256) void k_pack_x2(const float* __restrict__ X,
                                                 unsigned short* __restrict__ Bpk) {
  int G = blockIdx.x * 256 + threadIdx.x;   // 0 .. 4,194,303
  int col = G & 255;
  int kb  = (G >> 8) & 3;
  int qk  = (G >> 10) & 1;
  int kt  = (G >> 11) & 31;
  int jb  = G >> 16;
  int j   = jb * 256 + col;
  int mbase = kt * 32 + qk * 16 + kb * 4;
  unsigned v[4];
#pragma unroll
  for (int p = 0; p < 4; ++p) {
    int m = mbase + p;
    int j1 = j + 1;
    float f0 = (j1 < TT) ? X[(size_t)m * TT + j1] : 0.0f;  // s=0
    float f1 = X[(size_t)m * TT + j];                      // s=1
    v[p] = (unsigned)f2bf(f0) | ((unsigned)f2bf(f1) << 16);
  }
  uint4 w; w.x = v[0]; w.y = v[1]; w.z = v[2]; w.w = v[3];
  *reinterpret_cast<uint4*>(Bpk + (size_t)G * 8) = w;
}

// ---- kernel 4: 256x256 pipelined GEMM, K'=2048 ----
// 4 phases/K-tile: MFMA(p) overlaps ds_reads(p+1) via frag register double-buffer.
// vmcnt(6) at p0/p2 end (drains exactly the half-tile the NEXT phase reads).
__global__ __launch_bounds__(512, 2) void k_gemm(const char* __restrict__ Apk,
                                                 const char* __restrict__ Bpk,
                                                 float* __restrict__ Y) {
  __shared__ char lds[131072];  // 2 buf x { A 32K (h0|h1) | B 32K (h0|h1) }
  int bid = blockIdx.x;
  int swz = (bid & 7) * 32 + (bid >> 3);   // XCD-contiguous work chunks
  int jb = swz >> 2, mb = swz & 3;
  int tid = threadIdx.x;
  int lane = tid & 63, wv = tid >> 6;
  int wm = wv >> 2, wn = wv & 3;           // wave out: rows wm*128, cols wn*64
  int kb = lane >> 4, ml = lane & 15;
  const char* Asrc = Apk + (size_t)mb * (NKT * 2 * 16384);
  const char* Bsrc = Bpk + (size_t)jb * (NKT * 2 * 16384);

  fx4 acc[2][4][4];
#pragma unroll
  for (int q = 0; q < 2; ++q)
#pragma unroll
    for (int a = 0; a < 4; ++a)
#pragma unroll
      for (int b = 0; b < 4; ++b) acc[q][a][b] = (fx4){0.f, 0.f, 0.f, 0.f};

  auto stage_half = [&](int tile, int isB, int qh) {
    char* dst = lds + (tile & 1) * 65536 + isB * 32768 + qh * 16384;
    const char* src = (isB ? Bsrc : Asrc) + ((size_t)(tile & (NKT - 1)) * 2 + qh) * 16384;
    gll16(src + tid * 16, dst + tid * 16);
    gll16(src + (size_t)(tid + 512) * 16, dst + (tid + 512) * 16);
  };

#define READ_A(dst, t, qk, qm)                                                      \
  do {                                                                              \
    const char* Ah_ = lds + ((t) & 1) * 65536 + (qk) * 16384;                       \
    _Pragma("unroll") for (int mf = 0; mf < 4; ++mf)                                \
      dst[mf] = *(const s16x8*)(Ah_ +                                               \
          (size_t)(kb * 256 + wm * 128 + (qm) * 64 + mf * 16 + ml) * 16);           \
  } while (0)
#define READ_B(dst, t, qk)                                                          \
  do {                                                                              \
    const char* Bh_ = lds + ((t) & 1) * 65536 + 32768 + (qk) * 16384;               \
    _Pragma("unroll") for (int nf = 0; nf < 4; ++nf)                                \
      dst[nf] = *(const s16x8*)(Bh_ +                                               \
          (size_t)(kb * 256 + wn * 64 + nf * 16 + ml) * 16);                        \
  } while (0)
#define MFMA16(acc_, a_, b_)                                                        \
  do {                                                                              \
    __builtin_amdgcn_sched_barrier(0);                                              \
    __builtin_amdgcn_s_setprio(1);                                                  \
    _Pragma("unroll") for (int mf = 0; mf < 4; ++mf)                                \
      _Pragma("unroll") for (int nf = 0; nf < 4; ++nf)                              \
        acc_[mf][nf] = __builtin_amdgcn_mfma_f32_16x16x32_bf16(                     \
            __builtin_bit_cast(bfx8, a_[mf]), __builtin_bit_cast(bfx8, b_[nf]),     \
            acc_[mf][nf], 0, 0, 0);                                                 \
    __builtin_amdgcn_s_setprio(0);                                                  \
    __builtin_amdgcn_sched_barrier(0);                                              \
  } while (0)

  s16x8 aA[4], aB[4], bA[4], bB[4];

  // prologue: h0 t0 (drained), h1 t0 + h0 t1 (8 outstanding = steady state)
  stage_half(0, 0, 0); stage_half(0, 1, 0);
  stage_half(0, 0, 1); stage_half(0, 1, 1);
  stage_half(1, 0, 0); stage_half(1, 1, 0);
  asm volatile("s_waitcnt vmcnt(8)" ::: "memory");
  __builtin_amdgcn_s_barrier();
  READ_A(aA, 0, 0, 0);
  READ_B(bA, 0, 0);

  for (int kt = 0; kt < NKT; ++kt) {
    // p0 (qk0,qm0): MFMA(aA,bA)->acc0; prefetch aB<-A(kt,0,1); stage A h1 kt+1
    READ_A(aB, kt, 0, 1);
    stage_half(kt + 1, 0, 1);
    MFMA16(acc[0], aA, bA);
    asm volatile("s_waitcnt vmcnt(6)" ::: "memory");   // h1(kt) visible
    __builtin_amdgcn_s_barrier();
    // p1 (qk0,qm1): MFMA(aB,bA)->acc1; prefetch aA<-A(kt,1,0), bB<-B(kt,1); stage B h1 kt+1
    READ_A(aA, kt, 1, 0);
    READ_B(bB, kt, 1);
    stage_half(kt + 1, 1, 1);
    MFMA16(acc[1], aB, bA);
    __builtin_amdgcn_s_barrier();                       // h0(kt) reads drained -> p2 stage safe
    // p2 (qk1,qm0): MFMA(aA,bB)->acc0; prefetch aB<-A(kt,1,1); stage A h0 kt+2
    READ_A(aB, kt, 1, 1);
    stage_half(kt + 2, 0, 0);
    MFMA16(acc[0], aA, bB);
    asm volatile("s_waitcnt vmcnt(6)" ::: "memory");   // h0(kt+1) visible
    __builtin_amdgcn_s_barrier();
    // p3 (qk1,qm1): MFMA(aB,bB)->acc1; prefetch aA<-A(kt+1,0,0), bA<-B(kt+1,0); stage B h0 kt+2
    READ_A(aA, kt + 1, 0, 0);
    READ_B(bA, kt + 1, 0);
    stage_half(kt + 2, 1, 0);
    MFMA16(acc[1], aB, bB);
    __builtin_amdgcn_s_barrier();                       // h1(kt) reads drained -> p0 stage safe
  }
  asm volatile("s_waitcnt vmcnt(0)" ::: "memory");

  // epilogue: C/D layout col=lane&15, row=(lane>>4)*4+r
  int c0 = jb * 256 + wn * 64;
  int r0 = mb * 256 + wm * 128;
#pragma unroll
  for (int qm = 0; qm < 2; ++qm)
#pragma unroll
    for (int mf = 0; mf < 4; ++mf)
#pragma unroll
      for (int nf = 0; nf < 4; ++nf) {
        int c = c0 + nf * 16 + ml;
        if (c < NOUT) {
          int r = r0 + qm * 64 + mf * 16 + (lane >> 4) * 4;
#pragma unroll
          for (int i = 0; i < 4; ++i)
            Y[(size_t)(r + i) * NOUT + c] = acc[qm][mf][nf][i];
        }
      }
#undef READ_A
#undef READ_B
#undef MFMA16
}

extern "C" void kernel_launch(void* const* d_in, const int* in_sizes, int n_in,
                              void* d_out, int out_size, void* d_ws, size_t ws_size,
                              hipStream_t stream) {
  const float* X     = (const float*)d_in[0];
  const float* A     = (const float*)d_in[1];
  const float* alpha = (const float*)d_in[2];
  const float* beta0 = (const float*)d_in[3];
  const float* beta1 = (const float*)d_in[4];
  float* Y = (float*)d_out;
  char* ws = (char*)d_ws;
  char* Bpk = ws;                       // 64 MiB
  char* Apk = ws + APK_OFF;             // 4 MiB
  unsigned* B1 = (unsigned*)ws;         // 128 KiB, aliases Bpk (dead before pack)

  k_masks<<<dim3(1024), dim3(256), 0, stream>>>(A, B1);
  k_weights<<<dim3(1024), dim3(256), 0, stream>>>(B1, alpha, beta0, beta1,
                                                  (unsigned short*)Apk);
  k_pack_x2<<<dim3(16384), dim3(256), 0, stream>>>(X, (unsigned short*)Bpk);
  k_gemm<<<dim3(256), dim3(512), 0, stream>>>(Apk, Bpk, Y);
}